// Round 2
// baseline (6538.350 us; speedup 1.0000x reference)
//
#include <hip/hip_runtime.h>
#include <hip/hip_bf16.h>

// Persistent bidirectional LSTM for MI355X.
// B=32, T=512, H=512. 128 persistent WGs (2 dirs x 64), weights stationary in
// VGPRs (fp16 fragments), h broadcast via global fp16 double buffer with
// agent-scope flag sync per timestep. x-GEMM computed on the fly before the
// poll (hides sync latency). fp32 accumulate + fp32 cell state in registers.
//
// R1 post-mortem: bias was double-counted (both k-half waves seeded it) ->
// absmax 0.108. Fixed: kh==0 wave only. Also bf16 -> fp16 (8x finer mantissa,
// all values in range) to keep rounding error ~10x under the 1.41e-2 threshold.

#define HDIM 512
#define TDIM 512
#define BDIM 32
#define NWG  64     // workgroups per direction
#define NTHR 256

typedef float f32x4 __attribute__((ext_vector_type(4)));
typedef _Float16 half8 __attribute__((ext_vector_type(8)));

__device__ __forceinline__ float sigm(float x) { return 1.f / (1.f + __expf(-x)); }
__device__ __forceinline__ float tanh_f(float x) { return 1.f - 2.f / (__expf(2.f * x) + 1.f); }

// ws layout: [0,512): flags (2*NWG ints). [1024, 1024+131072): hbuf, fp16,
// [buf(2)][dir(2)][B][H]. Harness poisons ws with 0xAA each launch -> re-zero.
__global__ void init_ws_kernel(int* __restrict__ flags, int* __restrict__ hbuf_i) {
  int i = blockIdx.x * blockDim.x + threadIdx.x;
  if (i < 2 * NWG) flags[i] = 0;
  if (i < (2 * 2 * BDIM * HDIM) / 2) hbuf_i[i] = 0;  // 32768 dwords
}

__global__ __launch_bounds__(NTHR, 1)
void lstm_kernel(const float* __restrict__ x,
                 const float* __restrict__ WihF, const float* __restrict__ WhhF,
                 const float* __restrict__ bihF, const float* __restrict__ bhhF,
                 const float* __restrict__ WihB, const float* __restrict__ WhhB,
                 const float* __restrict__ bihB, const float* __restrict__ bhhB,
                 float* __restrict__ out,
                 int* __restrict__ flags, _Float16* __restrict__ hbuf) {
  const int blk = blockIdx.x;
  const int d = blk & 1;    // direction
  const int w = blk >> 1;   // 0..63: owns h-cols [w*8, w*8+8)
  const int tid = threadIdx.x;
  const int lane = tid & 63;
  const int wv = tid >> 6;  // wave 0..3
  const int nt = wv >> 1;   // n-tile (16 gate-cols each)
  const int kh = wv & 1;    // k-half (8 kblocks of 32)

  const float* Wih = d ? WihB : WihF;
  const float* Whh = d ? WhhB : WhhF;
  const float* bih = d ? bihB : bihF;
  const float* bhh = d ? bhhB : bhhF;

  // MFMA 16x16x32 lane roles. A: [m=lane&15][k=quad*8+j]; B: [k=quad*8+j][n=lane&15]
  // C/D: col=lane&15, row=(lane>>4)*4+reg  (m89-verified layouts)
  const int nn = lane & 15;
  const int quad = lane >> 4;
  const int n32 = nt * 16 + nn;        // col within WG's 32 gate-cols
  const int gg = n32 >> 3;             // gate 0..3 (i,f,g,o)
  const int jj = n32 & 7;              // h-col within slice
  const int gc = gg * HDIM + w * 8 + jj;  // global gate-col 0..2047

  // ---- stationary weight fragments (fp16 in VGPRs): 8 kblocks x 2 matrices ----
  half8 wihf[8], whhf[8];
#pragma unroll
  for (int kbi = 0; kbi < 8; ++kbi) {
    const int k0 = (kh * 8 + kbi) * 32 + quad * 8;
    const f32x4* pi = (const f32x4*)(Wih + (size_t)gc * HDIM + k0);
    const f32x4* ph = (const f32x4*)(Whh + (size_t)gc * HDIM + k0);
    f32x4 i0 = pi[0], i1 = pi[1], h0 = ph[0], h1 = ph[1];
    half8 a, b;
#pragma unroll
    for (int j = 0; j < 4; ++j) {
      a[j] = (_Float16)i0[j]; a[4 + j] = (_Float16)i1[j];
      b[j] = (_Float16)h0[j]; b[4 + j] = (_Float16)h1[j];
    }
    wihf[kbi] = a; whhf[kbi] = b;
  }
  // Bias seeded by the kh==0 wave ONLY (R1 bug: both waves seeded -> 2x bias).
  const float bseed = kh ? 0.f : (bih[gc] + bhh[gc]);

  // cell-update role: one (batch, h-col) per thread; c stays in a register
  const int cb = tid >> 3;
  const int cj = tid & 7;
  const int cmt = cb >> 4;
  const int creg = cb & 3;
  const int crow = (cb & 15) >> 2;
  float c = 0.f;

  __shared__ f32x4 part[8][64];  // [ (nt*2+kh)*2+mt ][lane] partial accs

  const int tstep = d ? -1 : 1;
  int tx = d ? (TDIM - 1) : 0;

  for (int s = 0; s < TDIM; ++s, tx += tstep) {
    f32x4 acc0 = {bseed, bseed, bseed, bseed};
    f32x4 acc1 = acc0;

    // ---- x phase: no cross-WG dependence; overlaps other WGs' step s-1 ----
#pragma unroll
    for (int kbi = 0; kbi < 8; ++kbi) {
      const int k0 = (kh * 8 + kbi) * 32 + quad * 8;
      {
        const f32x4* px = (const f32x4*)(x + ((size_t)nn * TDIM + tx) * HDIM + k0);
        f32x4 u0 = px[0], u1 = px[1];
        half8 ax;
#pragma unroll
        for (int j = 0; j < 4; ++j) { ax[j] = (_Float16)u0[j]; ax[4 + j] = (_Float16)u1[j]; }
        acc0 = __builtin_amdgcn_mfma_f32_16x16x32_f16(ax, wihf[kbi], acc0, 0, 0, 0);
      }
      {
        const f32x4* px = (const f32x4*)(x + ((size_t)(16 + nn) * TDIM + tx) * HDIM + k0);
        f32x4 u0 = px[0], u1 = px[1];
        half8 ax;
#pragma unroll
        for (int j = 0; j < 4; ++j) { ax[j] = (_Float16)u0[j]; ax[4 + j] = (_Float16)u1[j]; }
        acc1 = __builtin_amdgcn_mfma_f32_16x16x32_f16(ax, wihf[kbi], acc1, 0, 0, 0);
      }
    }

    // ---- wait for h_s from all 64 WGs of this direction ----
    if (s > 0) {
      const int* fl = flags + d * NWG;
      while (true) {
        int f = __hip_atomic_load(fl + lane, __ATOMIC_RELAXED, __HIP_MEMORY_SCOPE_AGENT);
        if (__ballot(f >= s) == ~0ull) break;
      }
      __builtin_amdgcn_fence(__ATOMIC_ACQUIRE, "agent");  // invalidate L1/L2
    }

    // ---- h phase: fp16 fragments straight from global double buffer ----
    const _Float16* hb = hbuf + (size_t)((s & 1) * 2 + d) * BDIM * HDIM;
#pragma unroll
    for (int kbi = 0; kbi < 8; ++kbi) {
      const int k0 = (kh * 8 + kbi) * 32 + quad * 8;
      half8 a0 = *(const half8*)(hb + nn * HDIM + k0);
      acc0 = __builtin_amdgcn_mfma_f32_16x16x32_f16(a0, whhf[kbi], acc0, 0, 0, 0);
      half8 a1 = *(const half8*)(hb + (16 + nn) * HDIM + k0);
      acc1 = __builtin_amdgcn_mfma_f32_16x16x32_f16(a1, whhf[kbi], acc1, 0, 0, 0);
    }

    // ---- cross-wave (k-half) reduction via LDS ----
    part[wv * 2 + 0][lane] = acc0;
    part[wv * 2 + 1][lane] = acc1;
    __syncthreads();

    // ---- cell update: thread (cb, cj) gathers its 4 gates ----
    float gv[4];
#pragma unroll
    for (int g4 = 0; g4 < 4; ++g4) {
      const int n32g = g4 * 8 + cj;
      const int ntg = n32g >> 4;
      const int ng = n32g & 15;
      const int lg = (crow << 4) | ng;
      f32x4 p0 = part[(ntg * 2 + 0) * 2 + cmt][lg];
      f32x4 p1 = part[(ntg * 2 + 1) * 2 + cmt][lg];
      gv[g4] = p0[creg] + p1[creg];
    }
    const float ig = sigm(gv[0]);
    const float fg = sigm(gv[1]);
    const float gt = tanh_f(gv[2]);
    const float og = sigm(gv[3]);
    c = fg * c + ig * gt;
    const float h = og * tanh_f(c);

    // publish h (fp16, alternate buffer) + write output (fp32)
    _Float16* hw = hbuf + (size_t)(((s + 1) & 1) * 2 + d) * BDIM * HDIM;
    hw[cb * HDIM + w * 8 + cj] = (_Float16)h;
    out[((size_t)cb * TDIM + tx) * (2 * HDIM) + d * HDIM + w * 8 + cj] = h;

    __syncthreads();  // per-wave vmcnt(0) drain: all h stores in L2 before release
    if (tid == 0) {
      __hip_atomic_store(flags + d * NWG + w, s + 1, __ATOMIC_RELEASE, __HIP_MEMORY_SCOPE_AGENT);
    }
  }
}

extern "C" void kernel_launch(void* const* d_in, const int* in_sizes, int n_in,
                              void* d_out, int out_size, void* d_ws, size_t ws_size,
                              hipStream_t stream) {
  const float* x    = (const float*)d_in[0];
  const float* WihF = (const float*)d_in[1];
  const float* WhhF = (const float*)d_in[2];
  const float* bihF = (const float*)d_in[3];
  const float* bhhF = (const float*)d_in[4];
  const float* WihB = (const float*)d_in[5];
  const float* WhhB = (const float*)d_in[6];
  const float* bihB = (const float*)d_in[7];
  const float* bhhB = (const float*)d_in[8];
  float* out = (float*)d_out;

  int* flags = (int*)d_ws;
  _Float16* hbuf = (_Float16*)((char*)d_ws + 1024);

  hipLaunchKernelGGL(init_ws_kernel, dim3(128), dim3(NTHR), 0, stream,
                     flags, (int*)hbuf);
  hipLaunchKernelGGL(lstm_kernel, dim3(2 * NWG), dim3(NTHR), 0, stream,
                     x, WihF, WhhF, bihF, bhhF, WihB, WhhB, bihB, bhhB,
                     out, flags, hbuf);
}

// Round 3
// 4495.631 us; speedup vs baseline: 1.4544x; 1.4544x over previous
//
#include <hip/hip_runtime.h>
#include <hip/hip_bf16.h>

// Persistent bidirectional LSTM for MI355X. B=32, T=512, H=512.
// 128 persistent WGs (2 dirs x 64), fp16 weight fragments stationary in VGPRs,
// h exchanged through a global double buffer each timestep.
//
// R2 post-mortem: 12.6 us/step, everything idle -> latency bound on sync.
// Cause: per-step agent-scope RELEASE store (buffer_wbl2 = full L2 writeback)
// + ACQUIRE fence (buffer_inv = full L2 invalidate) per WG per step.
// R3 fix: fence-free bypass protocol. All cross-WG traffic (h, flags) uses
// RELAXED agent-scope atomics (per-access sc0/sc1 -> coherent at L3, no
// cache-wide ops). Writer ordering: __syncthreads' vmcnt(0) drain before the
// flag store. Reader ordering: control dependency + bypass loads. x loads
// stay cached (L2 now stays warm -> FETCH_SIZE should drop).

#define HDIM 512
#define TDIM 512
#define BDIM 32
#define NWG  64     // workgroups per direction
#define NTHR 256

typedef float f32x4 __attribute__((ext_vector_type(4)));
typedef _Float16 half8 __attribute__((ext_vector_type(8)));
typedef unsigned long long u64x2 __attribute__((ext_vector_type(2)));

__device__ __forceinline__ float sigm(float x) { return 1.f / (1.f + __expf(-x)); }
__device__ __forceinline__ float tanh_f(float x) { return 1.f - 2.f / (__expf(2.f * x) + 1.f); }

// ws layout: [0,512): flags (2*NWG ints). [1024, 1024+131072): hbuf as ints,
// packed 2xfp16: [buf(2)][dir(2)][B][H/2]. Harness re-poisons ws each launch.
// Init MUST use bypass (agent atomic) stores: readers bypass L2, so cached
// init stores could sit dirty in some other XCD's L2, invisible to them.
__global__ void init_ws_kernel(int* __restrict__ flags, int* __restrict__ hbuf_i) {
  int i = blockIdx.x * blockDim.x + threadIdx.x;
  if (i < 2 * NWG)
    __hip_atomic_store(flags + i, 0, __ATOMIC_RELAXED, __HIP_MEMORY_SCOPE_AGENT);
  // 2 bufs * 2 dirs * 32 * 256 = 32768 ints; grid is exactly 32768 threads.
  __hip_atomic_store(hbuf_i + i, 0, __ATOMIC_RELAXED, __HIP_MEMORY_SCOPE_AGENT);
}

__global__ __launch_bounds__(NTHR, 1)
void lstm_kernel(const float* __restrict__ x,
                 const float* __restrict__ WihF, const float* __restrict__ WhhF,
                 const float* __restrict__ bihF, const float* __restrict__ bhhF,
                 const float* __restrict__ WihB, const float* __restrict__ WhhB,
                 const float* __restrict__ bihB, const float* __restrict__ bhhB,
                 float* __restrict__ out,
                 int* __restrict__ flags, int* __restrict__ hbuf) {
  const int blk = blockIdx.x;
  const int d = blk & 1;    // direction
  const int w = blk >> 1;   // 0..63: owns h-cols [w*8, w*8+8)
  const int tid = threadIdx.x;
  const int lane = tid & 63;
  const int wv = tid >> 6;  // wave 0..3
  const int nt = wv >> 1;   // n-tile (16 gate-cols each)
  const int kh = wv & 1;    // k-half (8 kblocks of 32)

  const float* Wih = d ? WihB : WihF;
  const float* Whh = d ? WhhB : WhhF;
  const float* bih = d ? bihB : bihF;
  const float* bhh = d ? bhhB : bhhF;

  // MFMA 16x16x32 lane roles. A: [m=lane&15][k=quad*8+j]; B: [k=quad*8+j][n=lane&15]
  // C/D: col=lane&15, row=(lane>>4)*4+reg  (m89-verified layouts)
  const int nn = lane & 15;
  const int quad = lane >> 4;
  const int n32 = nt * 16 + nn;        // col within WG's 32 gate-cols
  const int gg = n32 >> 3;             // gate 0..3 (i,f,g,o)
  const int jj = n32 & 7;              // h-col within slice
  const int gc = gg * HDIM + w * 8 + jj;  // global gate-col 0..2047

  // ---- stationary weight fragments (fp16 in VGPRs): 8 kblocks x 2 matrices ----
  half8 wihf[8], whhf[8];
#pragma unroll
  for (int kbi = 0; kbi < 8; ++kbi) {
    const int k0 = (kh * 8 + kbi) * 32 + quad * 8;
    const f32x4* pi = (const f32x4*)(Wih + (size_t)gc * HDIM + k0);
    const f32x4* ph = (const f32x4*)(Whh + (size_t)gc * HDIM + k0);
    f32x4 i0 = pi[0], i1 = pi[1], h0 = ph[0], h1 = ph[1];
    half8 a, b;
#pragma unroll
    for (int j = 0; j < 4; ++j) {
      a[j] = (_Float16)i0[j]; a[4 + j] = (_Float16)i1[j];
      b[j] = (_Float16)h0[j]; b[4 + j] = (_Float16)h1[j];
    }
    wihf[kbi] = a; whhf[kbi] = b;
  }
  // Bias seeded by the kh==0 wave ONLY (R1 bug: both waves seeded -> 2x bias).
  const float bseed = kh ? 0.f : (bih[gc] + bhh[gc]);

  // cell-update role: one (batch, h-col) per thread; c stays in a register
  const int cb = tid >> 3;
  const int cj = tid & 7;
  const int cmt = cb >> 4;
  const int creg = cb & 3;
  const int crow = (cb & 15) >> 2;
  float c = 0.f;

  __shared__ f32x4 part[8][64];  // [ (nt*2+kh)*2+mt ][lane] partial accs

  const int tstep = d ? -1 : 1;
  int tx = d ? (TDIM - 1) : 0;

  for (int s = 0; s < TDIM; ++s, tx += tstep) {
    f32x4 acc0 = {bseed, bseed, bseed, bseed};
    f32x4 acc1 = acc0;

    // ---- x phase: no cross-WG dependence; overlaps other WGs' step s-1 ----
#pragma unroll
    for (int kbi = 0; kbi < 8; ++kbi) {
      const int k0 = (kh * 8 + kbi) * 32 + quad * 8;
      {
        const f32x4* px = (const f32x4*)(x + ((size_t)nn * TDIM + tx) * HDIM + k0);
        f32x4 u0 = px[0], u1 = px[1];
        half8 ax;
#pragma unroll
        for (int j = 0; j < 4; ++j) { ax[j] = (_Float16)u0[j]; ax[4 + j] = (_Float16)u1[j]; }
        acc0 = __builtin_amdgcn_mfma_f32_16x16x32_f16(ax, wihf[kbi], acc0, 0, 0, 0);
      }
      {
        const f32x4* px = (const f32x4*)(x + ((size_t)(16 + nn) * TDIM + tx) * HDIM + k0);
        f32x4 u0 = px[0], u1 = px[1];
        half8 ax;
#pragma unroll
        for (int j = 0; j < 4; ++j) { ax[j] = (_Float16)u0[j]; ax[4 + j] = (_Float16)u1[j]; }
        acc1 = __builtin_amdgcn_mfma_f32_16x16x32_f16(ax, wihf[kbi], acc1, 0, 0, 0);
      }
    }

    // ---- wait for h_s from all 64 WGs of this direction (relaxed, no fence) ----
    if (s > 0) {
      const int* fl = flags + d * NWG;
      int f = __hip_atomic_load(fl + lane, __ATOMIC_RELAXED, __HIP_MEMORY_SCOPE_AGENT);
      while (__ballot(f >= s) != ~0ull) {
        __builtin_amdgcn_s_sleep(1);
        f = __hip_atomic_load(fl + lane, __ATOMIC_RELAXED, __HIP_MEMORY_SCOPE_AGENT);
      }
    }

    // ---- h phase: bypass loads (sc0/sc1) from the coherent point ----
    const unsigned long long* hb =
        (const unsigned long long*)(hbuf + (size_t)((s & 1) * 2 + d) * BDIM * (HDIM / 2));
#pragma unroll
    for (int kbi = 0; kbi < 8; ++kbi) {
      const int k0 = (kh * 8 + kbi) * 32 + quad * 8;  // fp16 index, /4 -> u64 index
      {
        const unsigned long long* p = hb + (nn * (HDIM / 4) + (k0 >> 2));
        u64x2 q;
        q[0] = __hip_atomic_load(p, __ATOMIC_RELAXED, __HIP_MEMORY_SCOPE_AGENT);
        q[1] = __hip_atomic_load(p + 1, __ATOMIC_RELAXED, __HIP_MEMORY_SCOPE_AGENT);
        half8 a0 = __builtin_bit_cast(half8, q);
        acc0 = __builtin_amdgcn_mfma_f32_16x16x32_f16(a0, whhf[kbi], acc0, 0, 0, 0);
      }
      {
        const unsigned long long* p = hb + ((16 + nn) * (HDIM / 4) + (k0 >> 2));
        u64x2 q;
        q[0] = __hip_atomic_load(p, __ATOMIC_RELAXED, __HIP_MEMORY_SCOPE_AGENT);
        q[1] = __hip_atomic_load(p + 1, __ATOMIC_RELAXED, __HIP_MEMORY_SCOPE_AGENT);
        half8 a1 = __builtin_bit_cast(half8, q);
        acc1 = __builtin_amdgcn_mfma_f32_16x16x32_f16(a1, whhf[kbi], acc1, 0, 0, 0);
      }
    }

    // ---- cross-wave (k-half) reduction via LDS ----
    part[wv * 2 + 0][lane] = acc0;
    part[wv * 2 + 1][lane] = acc1;
    __syncthreads();

    // ---- cell update: thread (cb, cj) gathers its 4 gates ----
    float gv[4];
#pragma unroll
    for (int g4 = 0; g4 < 4; ++g4) {
      const int n32g = g4 * 8 + cj;
      const int ntg = n32g >> 4;
      const int ng = n32g & 15;
      const int lg = (crow << 4) | ng;
      f32x4 p0 = part[(ntg * 2 + 0) * 2 + cmt][lg];
      f32x4 p1 = part[(ntg * 2 + 1) * 2 + cmt][lg];
      gv[g4] = p0[creg] + p1[creg];
    }
    const float ig = sigm(gv[0]);
    const float fg = sigm(gv[1]);
    const float gt = tanh_f(gv[2]);
    const float og = sigm(gv[3]);
    c = fg * c + ig * gt;
    const float h = og * tanh_f(c);

    // ---- publish h: pack 2xfp16 per int, even lane of each pair stores ----
    {
      const float hn = __shfl_xor(h, 1);  // neighbor's h (adjacent cj)
      int* hw = hbuf + (size_t)(((s + 1) & 1) * 2 + d) * BDIM * (HDIM / 2);
      if (!(tid & 1)) {
        const unsigned lo = (unsigned)__builtin_bit_cast(unsigned short, (_Float16)h);
        const unsigned hi = (unsigned)__builtin_bit_cast(unsigned short, (_Float16)hn);
        const int packed = (int)(lo | (hi << 16));
        __hip_atomic_store(hw + cb * (HDIM / 2) + ((w * 8 + cj) >> 1), packed,
                           __ATOMIC_RELAXED, __HIP_MEMORY_SCOPE_AGENT);
      }
      out[((size_t)cb * TDIM + tx) * (2 * HDIM) + d * HDIM + w * 8 + cj] = h;
    }

    // __syncthreads emits s_waitcnt vmcnt(0) per wave before s_barrier:
    // all write-through h stores are acked at the coherence point before
    // any wave proceeds -> plain relaxed flag store suffices as release.
    __syncthreads();
    if (tid == 0) {
      __hip_atomic_store(flags + d * NWG + w, s + 1, __ATOMIC_RELAXED, __HIP_MEMORY_SCOPE_AGENT);
    }
  }
}

extern "C" void kernel_launch(void* const* d_in, const int* in_sizes, int n_in,
                              void* d_out, int out_size, void* d_ws, size_t ws_size,
                              hipStream_t stream) {
  const float* x    = (const float*)d_in[0];
  const float* WihF = (const float*)d_in[1];
  const float* WhhF = (const float*)d_in[2];
  const float* bihF = (const float*)d_in[3];
  const float* bhhF = (const float*)d_in[4];
  const float* WihB = (const float*)d_in[5];
  const float* WhhB = (const float*)d_in[6];
  const float* bihB = (const float*)d_in[7];
  const float* bhhB = (const float*)d_in[8];
  float* out = (float*)d_out;

  int* flags = (int*)d_ws;
  int* hbuf = (int*)((char*)d_ws + 1024);

  hipLaunchKernelGGL(init_ws_kernel, dim3(128), dim3(NTHR), 0, stream,
                     flags, hbuf);
  hipLaunchKernelGGL(lstm_kernel, dim3(2 * NWG), dim3(NTHR), 0, stream,
                     x, WihF, WhhF, bihF, bhhF, WihB, WhhB, bihB, bhhB,
                     out, flags, hbuf);
}

// Round 4
// 3783.517 us; speedup vs baseline: 1.7281x; 1.1882x over previous
//
#include <hip/hip_runtime.h>
#include <hip/hip_bf16.h>

// Persistent bidirectional LSTM for MI355X. B=32, T=512, H=512.
// 128 persistent WGs (2 dirs x 64), fp16 weight fragments stationary in VGPRs.
//
// R3 post-mortem: 8.8 us/step, MfmaUtil 1.2% -> latency-bound on the exchange.
//   (1) poll storm: 32K lanes spinning bypass-loads on 8 flag lines throttled
//       the very flag stores being waited on;
//   (2) h fan-out: 8 MB/step of L2-bypass reads served from ~1K hot L3 lines
//       (every WG re-reads, duplicate loads between wave pairs).
// R4: (a) per-step padded counters, tid0-only poll + barrier broadcast;
//     (b) per-step h ring (addresses never reused within a launch) -> readers
//         use NORMAL CACHED loads (L1/L2 multicast; kernel-boundary acquire
//         invalidated stale lines; first touch is control-dependent on the
//         counter), writers stay write-through (sc0/sc1) so L3 is fresh.
//         Falls back to bypass double-buffer if ws_size is too small.
//     (c) publish counter before the out[] store (out is orderless).

#define HDIM 512
#define TDIM 512
#define BDIM 32
#define NWG  64     // workgroups per direction
#define NTHR 256
#define CSTRIDE 16  // ints per counter slot (64 B line padding)
#define SLOTS (TDIM + 1)

typedef float f32x4 __attribute__((ext_vector_type(4)));
typedef _Float16 half8 __attribute__((ext_vector_type(8)));
typedef unsigned long long u64x2 __attribute__((ext_vector_type(2)));

#define SLICE_INTS (BDIM * HDIM / 2)   // 8192 ints = 32 KB per (step,dir) slice

__device__ __forceinline__ float sigm(float x) { return 1.f / (1.f + __expf(-x)); }
__device__ __forceinline__ float tanh_f(float x) { return 1.f - 2.f / (__expf(2.f * x) + 1.f); }

// ws layout: [0, 65664): counters, int cnt[(d*SLOTS+s)*CSTRIDE].
// [65664, ...): hbuf slices [t][dir][B][H/2] packed 2xfp16 per int.
// Ring mode: t in [0,513). Dbuf mode: t in [0,2).
__global__ void init_ws_kernel(int* __restrict__ cnt, int* __restrict__ hbuf_i) {
  int i = blockIdx.x * blockDim.x + threadIdx.x;
  if (i < 2 * SLOTS * CSTRIDE)
    __hip_atomic_store(cnt + i, 0, __ATOMIC_RELAXED, __HIP_MEMORY_SCOPE_AGENT);
  // slice 0 (both dirs) must be zeros (h0 = 0): first 2*SLICE_INTS ints.
  if (i < 2 * SLICE_INTS)
    __hip_atomic_store(hbuf_i + i, 0, __ATOMIC_RELAXED, __HIP_MEMORY_SCOPE_AGENT);
}

template <bool RING>
__global__ __launch_bounds__(NTHR, 1)
void lstm_kernel(const float* __restrict__ x,
                 const float* __restrict__ WihF, const float* __restrict__ WhhF,
                 const float* __restrict__ bihF, const float* __restrict__ bhhF,
                 const float* __restrict__ WihB, const float* __restrict__ WhhB,
                 const float* __restrict__ bihB, const float* __restrict__ bhhB,
                 float* __restrict__ out,
                 int* __restrict__ cnt, int* __restrict__ hbuf) {
  const int blk = blockIdx.x;
  const int d = blk & 1;    // direction
  const int w = blk >> 1;   // 0..63: owns h-cols [w*8, w*8+8)
  const int tid = threadIdx.x;
  const int lane = tid & 63;
  const int wv = tid >> 6;  // wave 0..3
  const int nt = wv >> 1;   // n-tile (16 gate-cols each)
  const int kh = wv & 1;    // k-half (8 kblocks of 32)

  const float* Wih = d ? WihB : WihF;
  const float* Whh = d ? WhhB : WhhF;
  const float* bih = d ? bihB : bihF;
  const float* bhh = d ? bhhB : bhhF;

  // MFMA 16x16x32 lane roles. A: [m=lane&15][k=quad*8+j]; B: [k=quad*8+j][n=lane&15]
  // C/D: col=lane&15, row=(lane>>4)*4+reg  (m89-verified layouts)
  const int nn = lane & 15;
  const int quad = lane >> 4;
  const int n32 = nt * 16 + nn;        // col within WG's 32 gate-cols
  const int gg = n32 >> 3;             // gate 0..3 (i,f,g,o)
  const int jj = n32 & 7;              // h-col within slice
  const int gc = gg * HDIM + w * 8 + jj;  // global gate-col 0..2047

  // ---- stationary weight fragments (fp16 in VGPRs): 8 kblocks x 2 matrices ----
  half8 wihf[8], whhf[8];
#pragma unroll
  for (int kbi = 0; kbi < 8; ++kbi) {
    const int k0 = (kh * 8 + kbi) * 32 + quad * 8;
    const f32x4* pi = (const f32x4*)(Wih + (size_t)gc * HDIM + k0);
    const f32x4* ph = (const f32x4*)(Whh + (size_t)gc * HDIM + k0);
    f32x4 i0 = pi[0], i1 = pi[1], h0 = ph[0], h1 = ph[1];
    half8 a, b;
#pragma unroll
    for (int j = 0; j < 4; ++j) {
      a[j] = (_Float16)i0[j]; a[4 + j] = (_Float16)i1[j];
      b[j] = (_Float16)h0[j]; b[4 + j] = (_Float16)h1[j];
    }
    wihf[kbi] = a; whhf[kbi] = b;
  }
  // Bias seeded by the kh==0 wave ONLY.
  const float bseed = kh ? 0.f : (bih[gc] + bhh[gc]);

  // cell-update role: one (batch, h-col) per thread; c stays in a register
  const int cb = tid >> 3;
  const int cj = tid & 7;
  const int cmt = cb >> 4;
  const int creg = cb & 3;
  const int crow = (cb & 15) >> 2;
  float c = 0.f;

  __shared__ f32x4 part[8][64];  // [ (nt*2+kh)*2+mt ][lane] partial accs

  const int tstep = d ? -1 : 1;
  int tx = d ? (TDIM - 1) : 0;

  for (int s = 0; s < TDIM; ++s, tx += tstep) {
    f32x4 acc0 = {bseed, bseed, bseed, bseed};
    f32x4 acc1 = acc0;

    // ---- x phase: no cross-WG dependence; overlaps other WGs' step s-1 ----
#pragma unroll
    for (int kbi = 0; kbi < 8; ++kbi) {
      const int k0 = (kh * 8 + kbi) * 32 + quad * 8;
      {
        const f32x4* px = (const f32x4*)(x + ((size_t)nn * TDIM + tx) * HDIM + k0);
        f32x4 u0 = px[0], u1 = px[1];
        half8 ax;
#pragma unroll
        for (int j = 0; j < 4; ++j) { ax[j] = (_Float16)u0[j]; ax[4 + j] = (_Float16)u1[j]; }
        acc0 = __builtin_amdgcn_mfma_f32_16x16x32_f16(ax, wihf[kbi], acc0, 0, 0, 0);
      }
      {
        const f32x4* px = (const f32x4*)(x + ((size_t)(16 + nn) * TDIM + tx) * HDIM + k0);
        f32x4 u0 = px[0], u1 = px[1];
        half8 ax;
#pragma unroll
        for (int j = 0; j < 4; ++j) { ax[j] = (_Float16)u0[j]; ax[4 + j] = (_Float16)u1[j]; }
        acc1 = __builtin_amdgcn_mfma_f32_16x16x32_f16(ax, wihf[kbi], acc1, 0, 0, 0);
      }
    }

    // ---- wait: tid0 polls the per-step counter, barrier broadcasts ----
    if (s > 0) {
      if (tid == 0) {
        const int* pc = cnt + (size_t)(d * SLOTS + s) * CSTRIDE;
        while (__hip_atomic_load(pc, __ATOMIC_RELAXED, __HIP_MEMORY_SCOPE_AGENT) < NWG) {}
      }
      __syncthreads();  // broadcast + compiler barrier (no hoisting of h loads)
    }

    // ---- h phase ----
    if (RING) {
      // cached loads; addresses unique per step -> no staleness possible.
      const _Float16* hb =
          (const _Float16*)(hbuf + ((size_t)s * 2 + d) * SLICE_INTS);
#pragma unroll
      for (int kbi = 0; kbi < 8; ++kbi) {
        const int k0 = (kh * 8 + kbi) * 32 + quad * 8;
        half8 a0 = *(const half8*)(hb + nn * HDIM + k0);
        acc0 = __builtin_amdgcn_mfma_f32_16x16x32_f16(a0, whhf[kbi], acc0, 0, 0, 0);
        half8 a1 = *(const half8*)(hb + (16 + nn) * HDIM + k0);
        acc1 = __builtin_amdgcn_mfma_f32_16x16x32_f16(a1, whhf[kbi], acc1, 0, 0, 0);
      }
    } else {
      // bypass loads (sc0/sc1) from the coherence point; double buffer.
      const unsigned long long* hb = (const unsigned long long*)(
          hbuf + ((size_t)(s & 1) * 2 + d) * SLICE_INTS);
#pragma unroll
      for (int kbi = 0; kbi < 8; ++kbi) {
        const int k0 = (kh * 8 + kbi) * 32 + quad * 8;  // fp16 idx; /4 -> u64 idx
        {
          const unsigned long long* p = hb + (nn * (HDIM / 4) + (k0 >> 2));
          u64x2 q;
          q[0] = __hip_atomic_load(p, __ATOMIC_RELAXED, __HIP_MEMORY_SCOPE_AGENT);
          q[1] = __hip_atomic_load(p + 1, __ATOMIC_RELAXED, __HIP_MEMORY_SCOPE_AGENT);
          half8 a0 = __builtin_bit_cast(half8, q);
          acc0 = __builtin_amdgcn_mfma_f32_16x16x32_f16(a0, whhf[kbi], acc0, 0, 0, 0);
        }
        {
          const unsigned long long* p = hb + ((16 + nn) * (HDIM / 4) + (k0 >> 2));
          u64x2 q;
          q[0] = __hip_atomic_load(p, __ATOMIC_RELAXED, __HIP_MEMORY_SCOPE_AGENT);
          q[1] = __hip_atomic_load(p + 1, __ATOMIC_RELAXED, __HIP_MEMORY_SCOPE_AGENT);
          half8 a1 = __builtin_bit_cast(half8, q);
          acc1 = __builtin_amdgcn_mfma_f32_16x16x32_f16(a1, whhf[kbi], acc1, 0, 0, 0);
        }
      }
    }

    // ---- cross-wave (k-half) reduction via LDS ----
    part[wv * 2 + 0][lane] = acc0;
    part[wv * 2 + 1][lane] = acc1;
    __syncthreads();

    // ---- cell update: thread (cb, cj) gathers its 4 gates ----
    float gv[4];
#pragma unroll
    for (int g4 = 0; g4 < 4; ++g4) {
      const int n32g = g4 * 8 + cj;
      const int ntg = n32g >> 4;
      const int ng = n32g & 15;
      const int lg = (crow << 4) | ng;
      f32x4 p0 = part[(ntg * 2 + 0) * 2 + cmt][lg];
      f32x4 p1 = part[(ntg * 2 + 1) * 2 + cmt][lg];
      gv[g4] = p0[creg] + p1[creg];
    }
    const float ig = sigm(gv[0]);
    const float fg = sigm(gv[1]);
    const float gt = tanh_f(gv[2]);
    const float og = sigm(gv[3]);
    c = fg * c + ig * gt;
    const float h = og * tanh_f(c);

    // ---- publish h: pack 2xfp16 per int, even lane of each pair stores ----
    const float hn = __shfl_xor(h, 1);  // neighbor's h (adjacent cj)
    {
      const size_t tdst = RING ? (size_t)(s + 1) : (size_t)((s + 1) & 1);
      int* hw = hbuf + (tdst * 2 + d) * SLICE_INTS;
      if (!(tid & 1)) {
        const unsigned lo = (unsigned)__builtin_bit_cast(unsigned short, (_Float16)h);
        const unsigned hi = (unsigned)__builtin_bit_cast(unsigned short, (_Float16)hn);
        const int packed = (int)(lo | (hi << 16));
        __hip_atomic_store(hw + cb * (HDIM / 2) + ((w * 8 + cj) >> 1), packed,
                           __ATOMIC_RELAXED, __HIP_MEMORY_SCOPE_AGENT);
      }
    }

    // __syncthreads emits s_waitcnt vmcnt(0) per wave before s_barrier:
    // all write-through h stores are acked at the coherence point before
    // tid0 increments the next-step counter (device-scope atomic, m20).
    __syncthreads();
    if (tid == 0) {
      __hip_atomic_fetch_add(cnt + (size_t)(d * SLOTS + s + 1) * CSTRIDE, 1,
                             __ATOMIC_RELAXED, __HIP_MEMORY_SCOPE_AGENT);
    }

    // out store AFTER publish: orderless wrt the sync protocol, drained by
    // the next step's barriers / kernel-end release.
    out[((size_t)cb * TDIM + tx) * (2 * HDIM) + d * HDIM + w * 8 + cj] = h;
  }
}

extern "C" void kernel_launch(void* const* d_in, const int* in_sizes, int n_in,
                              void* d_out, int out_size, void* d_ws, size_t ws_size,
                              hipStream_t stream) {
  const float* x    = (const float*)d_in[0];
  const float* WihF = (const float*)d_in[1];
  const float* WhhF = (const float*)d_in[2];
  const float* bihF = (const float*)d_in[3];
  const float* bhhF = (const float*)d_in[4];
  const float* WihB = (const float*)d_in[5];
  const float* WhhB = (const float*)d_in[6];
  const float* bihB = (const float*)d_in[7];
  const float* bhhB = (const float*)d_in[8];
  float* out = (float*)d_out;

  int* cnt = (int*)d_ws;
  const size_t cnt_bytes = (size_t)2 * SLOTS * CSTRIDE * 4;  // 65664 B
  int* hbuf = (int*)((char*)d_ws + cnt_bytes);

  // Ring mode needs slices t=0..512 for both dirs.
  const size_t ring_bytes = cnt_bytes + (size_t)SLOTS * 2 * SLICE_INTS * 4;
  const bool ring = (ws_size >= ring_bytes);

  hipLaunchKernelGGL(init_ws_kernel, dim3(128), dim3(NTHR), 0, stream, cnt, hbuf);
  if (ring) {
    hipLaunchKernelGGL((lstm_kernel<true>), dim3(2 * NWG), dim3(NTHR), 0, stream,
                       x, WihF, WhhF, bihF, bhhF, WihB, WhhB, bihB, bhhB,
                       out, cnt, hbuf);
  } else {
    hipLaunchKernelGGL((lstm_kernel<false>), dim3(2 * NWG), dim3(NTHR), 0, stream,
                       x, WihF, WhhF, bihF, bhhF, WihB, WhhB, bihB, bhhB,
                       out, cnt, hbuf);
  }
}